// Round 1
// baseline (715.603 us; speedup 1.0000x reference)
//
#include <hip/hip_runtime.h>

// Problem constants: N=1e6 rows, D_IN=128, D_OUT=64, C=64.
#define C_CLASSES 64
#define D_IN 128
#define D_OUT 64
#define CHUNK 32                    // rows per K-chunk (one 16x16x32 K-step)
#define CHUNK_FLTS (CHUNK * D_IN)   // 4096 floats = 16 KB
#define GSUM_FLTS (C_CLASSES * D_IN) // 8192
#define NBLK 1024                   // seg_mm grid (4 blocks/CU, LDS 32KB each)

// protos = (seg_sum(X)@W + cnt*b)/max(cnt,1); seg_sum(X) = OneHot(labels)^T @ X
//
// R4: two fixes vs R3 (707.9 us, ~0.73 TB/s = 11% of HBM):
//  (1) __syncthreads() drains vmcnt(0) -> double buffer never pipelined.
//      Replaced with raw s_barrier + counted vmcnt(6) (T3/T4-lite): next-chunk
//      DMA + label loads stay in flight across the whole iteration.
//  (2) epilogue did 8.4M contended global atomics (1024 blocks x 8192 addrs).
//      Replaced with non-atomic per-block partials[1024][8192] (32 MB ws) +
//      a coalesced reduce kernel. Atomic fallback if ws_size too small.

typedef __attribute__((ext_vector_type(8))) __bf16 bf16x8;
typedef __attribute__((ext_vector_type(8))) unsigned short us8;
typedef __attribute__((ext_vector_type(4))) float f32x4;

union frag_cast { us8 u; bf16x8 b; };

// float -> bf16 round-to-nearest-even.
__device__ __forceinline__ unsigned short f2bf(float f) {
    unsigned u = __float_as_uint(f);
    unsigned r = u + 0x7FFFu + ((u >> 16) & 1u);
    return (unsigned short)(r >> 16);
}

// Async global->LDS, 16B per lane. LDS dest = wave-uniform base + lane*16.
__device__ __forceinline__ void stage16(const float* g, float* l) {
    __builtin_amdgcn_global_load_lds(
        (const __attribute__((address_space(1))) unsigned int*)g,
        (__attribute__((address_space(3))) unsigned int*)l, 16, 0, 0);
}

// --- Kernel 1: S = OneHot^T @ X via mfma_f32_16x16x32_bf16, LDS-staged -----
// Block = 256 thr = 4 waves; block covers full 64x128 output. Wave w owns
// cols [32w,32w+32): 4 class-tiles x 2 col-tiles = 8 acc frags.
// Layouts (R2-verified): A[m][k] m=lane&15,k=quad*8+j; B[k][n] n=lane&15;
// D[m][n] m=quad*4+r, n=lane&15.
//
// Sync structure (new template; hazard analysis):
//   prologue: STAGE(buf0, chunk0) + labels0            [6 vmem ops in queue]
//   iter i:  A: STAGE(buf[cur^1], chunk i+1) + labels  [+6 ops]
//            B: s_waitcnt vmcnt(6); s_barrier   // own chunk-i DMA done, then
//                                               // barrier => ALL waves' done
//            C: ds_read buf[cur] frags + MFMA   // lgkmcnt auto-inserted
//            D: s_barrier (memory-clobber asm)  // all readers done before
//                                               // iter i+1 overwrites buf[cur]
//   vmcnt retires in order, so vmcnt(6) == "everything older than this
//   iteration's 6 prefetch ops is complete". Last iter uses vmcnt(0).
//   hasNext is block-uniform -> barriers are uniform.
__global__ __launch_bounds__(256) void seg_mm_kernel(
    const float* __restrict__ x, const int* __restrict__ labels,
    float* __restrict__ gsum, float* __restrict__ partials, int n)
{
    __shared__ float buf[2][CHUNK_FLTS];   // 2 x 16 KB double buffer

    const int lane = threadIdx.x & 63;
    const int wave = threadIdx.x >> 6;     // 0..3
    const int n16  = lane & 15;
    const int quad = lane >> 4;            // 0..3
    const int cb   = wave * 32;            // wave's column base

    f32x4 acc[4][2];
#pragma unroll
    for (int t = 0; t < 4; ++t)
#pragma unroll
        for (int u = 0; u < 2; ++u)
            acc[t][u] = (f32x4){0.f, 0.f, 0.f, 0.f};

    const int stride = (int)gridDim.x * CHUNK;
    const int rb0    = (int)blockIdx.x * CHUNK;
    const int lslice = wave * 256;         // wave-uniform LDS float offset
    const int gslice = lslice + lane * 4;  // per-lane float offset in chunk

    // Prologue: stage chunk 0 (4 DMA ops) then its labels (2 dwordx4 loads).
#pragma unroll
    for (int r = 0; r < 4; ++r)
        stage16(x + (size_t)rb0 * D_IN + r * 1024 + gslice,
                &buf[0][r * 1024 + lslice]);
    int4 pl0 = *(const int4*)(labels + rb0 + quad * 8);
    int4 pl1 = *(const int4*)(labels + rb0 + quad * 8 + 4);

    int bufi = 0;
    for (int rb = rb0; rb < n; rb += stride, bufi ^= 1) {
        const int rbn = rb + stride;
        const bool hasNext = rbn < n;      // block-uniform
        int4 pn0, pn1;
        if (hasNext) {                     // issue next chunk: 4 DMA + 2 loads
#pragma unroll
            for (int r = 0; r < 4; ++r)
                stage16(x + (size_t)rbn * D_IN + r * 1024 + gslice,
                        &buf[bufi ^ 1][r * 1024 + lslice]);
            pn0 = *(const int4*)(labels + rbn + quad * 8);
            pn1 = *(const int4*)(labels + rbn + quad * 8 + 4);
        }

        // Counted wait: 6 younger vmem ops (next chunk) stay in flight.
        if (hasNext) {
            asm volatile("s_waitcnt vmcnt(6)\n\ts_barrier" ::: "memory");
        } else {
            asm volatile("s_waitcnt vmcnt(0)\n\ts_barrier" ::: "memory");
        }

        const int labv[8] = {pl0.x, pl0.y, pl0.z, pl0.w,
                             pl1.x, pl1.y, pl1.z, pl1.w};

        // B frags from LDS: buf[k*128 + cb + u*16 + n16], k = quad*8+j.
        const float* lb = &buf[bufi][(quad * 8) * D_IN + cb + n16];
        frag_cast bfrag[2];
#pragma unroll
        for (int u = 0; u < 2; ++u)
#pragma unroll
            for (int j = 0; j < 8; ++j)
                bfrag[u].u[j] = f2bf(lb[j * D_IN + u * 16]);

        // A frags: one-hot from prefetched labels.
        frag_cast afrag[4];
#pragma unroll
        for (int t = 0; t < 4; ++t)
#pragma unroll
            for (int j = 0; j < 8; ++j)
                afrag[t].u[j] = (labv[j] == t * 16 + n16)
                                    ? (unsigned short)0x3F80u : (unsigned short)0u;

#pragma unroll
        for (int t = 0; t < 4; ++t)
#pragma unroll
            for (int u = 0; u < 2; ++u)
                acc[t][u] = __builtin_amdgcn_mfma_f32_16x16x32_bf16(
                    afrag[t].b, bfrag[u].b, acc[t][u], 0, 0, 0);

        // All waves done reading buf[bufi] before iter i+1 overwrites it.
        asm volatile("s_barrier" ::: "memory");

        if (hasNext) { pl0 = pn0; pl1 = pn1; }
    }

    // Epilogue: D[class = 16t + quad*4 + r][col = cb + 16u + n16]
    if (partials) {
        float* prow = partials + (size_t)blockIdx.x * GSUM_FLTS;
#pragma unroll
        for (int t = 0; t < 4; ++t)
#pragma unroll
            for (int u = 0; u < 2; ++u)
#pragma unroll
                for (int r = 0; r < 4; ++r)
                    prow[(t * 16 + quad * 4 + r) * D_IN + cb + u * 16 + n16] =
                        acc[t][u][r];
    } else {
#pragma unroll
        for (int t = 0; t < 4; ++t)
#pragma unroll
            for (int u = 0; u < 2; ++u)
#pragma unroll
                for (int r = 0; r < 4; ++r)
                    unsafeAtomicAdd(
                        &gsum[(t * 16 + quad * 4 + r) * D_IN + cb + u * 16 + n16],
                        acc[t][u][r]);
    }
}

// --- Kernel 1b: fold partials[1024][8192] into gsum[8192] ------------------
// 65536 threads: col = t & 8191 (coalesced), 8 partial-groups of 128 rows
// each; one atomicAdd per (col, group) = 65k atomics total (negligible).
__global__ __launch_bounds__(256) void reduce_kernel(
    const float* __restrict__ partials, float* __restrict__ gsum)
{
    const int t   = (int)(blockIdx.x * blockDim.x + threadIdx.x); // 0..65535
    const int col = t & (GSUM_FLTS - 1);
    const int pg  = t >> 13;                                      // 0..7
    float a = 0.f;
#pragma unroll 8
    for (int p = 0; p < NBLK / 8; ++p)
        a += partials[(size_t)(pg * (NBLK / 8) + p) * GSUM_FLTS + col];
    unsafeAtomicAdd(&gsum[col], a);
}

// --- Kernel 2: class counts via wave ballot --------------------------------
__global__ __launch_bounds__(256) void count_kernel(
    const int* __restrict__ labels, float* __restrict__ gcnt, int n)
{
    const int lane = threadIdx.x & 63;
    const int gw   = (int)(blockIdx.x * blockDim.x + threadIdx.x) >> 6;
    const int nw   = (int)(gridDim.x * blockDim.x) >> 6;

    int cnt = 0;
    for (int base = gw * 64; base < n; base += nw * 64) {  // n % 64 == 0
        const int lab = labels[base + lane];
#pragma unroll
        for (int c = 0; c < C_CLASSES; ++c) {
            unsigned long long m = __ballot(lab == c);
            cnt += (lane == c) ? __popcll(m) : 0;
        }
    }
    unsafeAtomicAdd(&gcnt[lane], (float)cnt);  // lane == class
}

// --- Kernel 3: tiny GEMM + bias + normalize --------------------------------
__global__ __launch_bounds__(256) void proto_kernel(
    const float* __restrict__ gsum, const float* __restrict__ gcnt,
    const float* __restrict__ W, const float* __restrict__ b,
    float* __restrict__ out)
{
    const int t = (int)(blockIdx.x * blockDim.x + threadIdx.x);
    const int c = t >> 6;
    const int e = t & 63;

    const float* srow = gsum + (c << 7);
    float acc = 0.0f;
#pragma unroll
    for (int k = 0; k < D_IN; ++k)
        acc = fmaf(srow[k], W[k * D_OUT + e], acc);

    const float cnt = gcnt[c];
    out[(c << 6) + e] = (acc + cnt * b[e]) / fmaxf(cnt, 1.0f);
}

extern "C" void kernel_launch(void* const* d_in, const int* in_sizes, int n_in,
                              void* d_out, int out_size, void* d_ws, size_t ws_size,
                              hipStream_t stream)
{
    const float* x      = (const float*)d_in[0];
    const int*   labels = (const int*)d_in[1];
    const float* W      = (const float*)d_in[2];
    const float* b      = (const float*)d_in[3];
    float*       out    = (float*)d_out;

    float* gsum = (float*)d_ws;                  // [64*128]
    float* gcnt = gsum + GSUM_FLTS;              // [64]
    float* partials = gcnt + C_CLASSES;          // [NBLK][8192] if it fits

    const int n = in_sizes[0] / D_IN;            // 1,000,000 (multiple of 64)

    const size_t need = (size_t)(GSUM_FLTS + C_CLASSES) * sizeof(float)
                      + (size_t)NBLK * GSUM_FLTS * sizeof(float);  // ~33.6 MB
    const bool use_partials = ws_size >= need;

    hipMemsetAsync(d_ws, 0, (GSUM_FLTS + C_CLASSES) * sizeof(float), stream);

    // 1024 blocks x 4 waves, 32 KB LDS each -> 4 blocks/CU, 16 waves/CU.
    seg_mm_kernel<<<NBLK, 256, 0, stream>>>(
        x, labels, gsum, use_partials ? partials : (float*)nullptr, n);

    count_kernel<<<256, 256, 0, stream>>>(labels, gcnt, n);

    if (use_partials)
        reduce_kernel<<<(8 * GSUM_FLTS) / 256, 256, 0, stream>>>(partials, gsum);

    proto_kernel<<<(C_CLASSES * D_OUT) / 256, 256, 0, stream>>>(gsum, gcnt, W, b, out);
}